// Round 4
// baseline (512.771 us; speedup 1.0000x reference)
//
#include <hip/hip_runtime.h>

#define N_WIDTH 64
#define N_ORDER 4
#define N_ELEMENTS 250
#define N_NODES 1001                        // N_ELEMENTS*N_ORDER+1
#define N_COLL 200
#define NDIM 2
#define MM 5                                // N_ORDER+1
#define ROW (N_NODES * NDIM)                // 2002 floats per (k) row
#define SAMPLE_SLICE (N_WIDTH * ROW)        // 128128 floats per sample
#define BUF_ELEMS ((long)N_COLL * SAMPLE_SLICE)  // 25,625,600 floats per buffer
#define BUF_BYTES (BUF_ELEMS * 4)                // 102,502,400 bytes per buffer
#define RED_BLOCKS 64

__device__ __forceinline__ float wave_reduce(float v) {
    for (int off = 32; off > 0; off >>= 1) v += __shfl_down(v, off, 64);
    return v;
}

// ---------------------------------------------------------------------------
// Bulk copy is now done by three driver D2D memcpys (see kernel_launch) —
// the driver blit path sustains ~6.4 TB/s (same machinery as the 80%-peak
// harness fills), beating our hand-rolled 5.0 TB/s interleaved loop.
// This kernel only rewrites the sample slice with scatter values and
// computes the t/dt/ddt reductions. Block k owns row k. Runs AFTER the
// memcpys (stream-ordered), so its slice writes land last. Math verbatim
// from the harness-verified kernel.
// ---------------------------------------------------------------------------
__global__ __launch_bounds__(256) void reduce_kernel(
        const float* __restrict__ x,
        const int* __restrict__ flagp,
        const int* __restrict__ samplep,
        const float* __restrict__ weight,
        const float* __restrict__ phi_in,
        const float* __restrict__ dphi_in,
        const float* __restrict__ ddphi_in,
        float* __restrict__ phi_out,
        float* __restrict__ dphi_out,
        float* __restrict__ ddphi_out,
        float* __restrict__ t_out) {
    const int sample = *samplep;
    const int tid = threadIdx.x;
    const int k = blockIdx.x;
    const int flag = *flagp;
    const long wbase = (long)k * ROW;
    const long base = (long)sample * SAMPLE_SLICE + wbase;

    // element lookup per input dimension (same for every k)
    float xs[NDIM];
    int nl[NDIM];
    for (int q = 0; q < NDIM; ++q) {
        xs[q] = (float)(N_NODES - 1) * x[q];            // X_MIN=0, X_MAX=1
        float id_el = floorf(xs[q] / (float)N_ORDER);
        id_el = fminf(fmaxf(id_el, 0.0f), (float)(N_ELEMENTS - 1));
        nl[q] = (int)(id_el * (float)N_ORDER);
    }

    // Lagrange bases on nodes {-1,-0.5,0,0.5,1} for both d channels
    const float nodes[MM] = {-1.0f, -0.5f, 0.0f, 0.5f, 1.0f};
    float L[NDIM][MM], dLv[NDIM][MM], ddLv[NDIM][MM];
    for (int d = 0; d < NDIM; ++d) {
        float xt = (xs[d] - ((float)nl[d] + 2.0f)) * 0.5f;
        float inv[MM][MM], r[MM][MM];
        for (int i = 0; i < MM; ++i)
            for (int kk = 0; kk < MM; ++kk) {
                inv[i][kk] = (i == kk) ? 0.0f : 1.0f / (nodes[i] - nodes[kk]);
                r[i][kk] = (xt - nodes[kk]) * inv[i][kk];
            }
        for (int i = 0; i < MM; ++i) {
            float prod = 1.0f;
            for (int kk = 0; kk < MM; ++kk) if (kk != i) prod *= r[i][kk];
            L[d][i] = prod;

            float s = 0.0f;
            for (int j = 0; j < MM; ++j) if (j != i) {
                float pr = 1.0f;
                for (int kk = 0; kk < MM; ++kk) if (kk != i && kk != j) pr *= r[i][kk];
                s += inv[i][j] * pr;
            }
            dLv[d][i] = (i == MM - 1) ? s : 0.0f;  // reference quirk: only i==M-1 kept

            float ss = 0.0f;
            for (int j = 0; j < MM; ++j) if (j != i) {
                float s2 = 0.0f;
                for (int kk = 0; kk < MM; ++kk) if (kk != i && kk != j) {
                    float pr = 1.0f;
                    for (int l = 0; l < MM; ++l) if (l != i && l != j && l != kk) pr *= r[i][l];
                    s2 += inv[i][kk] * pr;
                }
                ss += inv[i][j] * s2;
            }
            ddLv[d][i] = ss;
        }
    }

    const float dx = 0.5f * (float)N_ORDER / (float)(N_NODES - 1);  // 0.002
    const float inv_dx = 1.0f / dx;
    const float inv_dx2 = inv_dx * inv_dx;

    float st = 0.0f, sdt = 0.0f, sddt = 0.0f;
    for (int i = tid; i < ROW; i += 256) {
        float v   = phi_in[base + i];
        float dv  = dphi_in[base + i];
        float ddv = ddphi_in[base + i];
        if (flag == 0) {
            int q = i >> 1;
            int d = i & 1;
            // final reference write at (q,d): largest valid p over dq ranges
            int p0 = q - nl[0];
            int p1 = q - nl[1];
            int p = -1;
            if (p0 >= 0 && p0 <= N_ORDER) p = p0;
            if (p1 >= 0 && p1 <= N_ORDER && p1 > p) p = p1;
            if (p >= 0) {
                v   = L[d][p];
                dv  = dLv[d][p] * inv_dx;
                ddv = ddLv[d][p] * inv_dx2;
            }
        }
        phi_out[base + i]   = v;
        dphi_out[base + i]  = dv;
        ddphi_out[base + i] = ddv;
        float wv = weight[wbase + i];
        st   += wv * v;
        sdt  += wv * dv;
        sddt += wv * ddv;
    }

    st = wave_reduce(st);
    sdt = wave_reduce(sdt);
    sddt = wave_reduce(sddt);

    __shared__ float sh[3][4];
    int lane = tid & 63;
    int wid = tid >> 6;
    if (lane == 0) { sh[0][wid] = st; sh[1][wid] = sdt; sh[2][wid] = sddt; }
    __syncthreads();
    if (tid == 0) {
        t_out[k]       = sh[0][0] + sh[0][1] + sh[0][2] + sh[0][3];
        t_out[64 + k]  = sh[1][0] + sh[1][1] + sh[1][2] + sh[1][3];
        t_out[128 + k] = sh[2][0] + sh[2][1] + sh[2][2] + sh[2][3];
    }
}

extern "C" void kernel_launch(void* const* d_in, const int* in_sizes, int n_in,
                              void* d_out, int out_size, void* d_ws, size_t ws_size,
                              hipStream_t stream) {
    const float* x        = (const float*)d_in[0];
    const int*   flagp    = (const int*)d_in[1];
    const int*   samplep  = (const int*)d_in[2];
    const float* weight   = (const float*)d_in[3];
    const float* phi_in   = (const float*)d_in[4];
    const float* dphi_in  = (const float*)d_in[5];
    const float* ddphi_in = (const float*)d_in[6];

    float* out = (float*)d_out;
    float* t_out     = out;             // 192 floats: t(64), dt(64), ddt(64)
    float* phi_out   = out + 192;       // 768 B offset -> 16B aligned
    float* dphi_out  = phi_out + BUF_ELEMS;
    float* ddphi_out = dphi_out + BUF_ELEMS;

    // Bulk pass-through via driver blit path (~6.4 TB/s). Full buffers,
    // including the sample slice — the reduce kernel overwrites that region
    // afterward (stream-ordered).
    hipMemcpyAsync(phi_out,   phi_in,   BUF_BYTES, hipMemcpyDeviceToDevice, stream);
    hipMemcpyAsync(dphi_out,  dphi_in,  BUF_BYTES, hipMemcpyDeviceToDevice, stream);
    hipMemcpyAsync(ddphi_out, ddphi_in, BUF_BYTES, hipMemcpyDeviceToDevice, stream);

    reduce_kernel<<<RED_BLOCKS, 256, 0, stream>>>(
        x, flagp, samplep, weight, phi_in, dphi_in, ddphi_in,
        phi_out, dphi_out, ddphi_out, t_out);
}

// Round 5
// 508.144 us; speedup vs baseline: 1.0091x; 1.0091x over previous
//
#include <hip/hip_runtime.h>

#define N_WIDTH 64
#define N_ORDER 4
#define N_ELEMENTS 250
#define N_NODES 1001                        // N_ELEMENTS*N_ORDER+1
#define N_COLL 200
#define NDIM 2
#define MM 5                                // N_ORDER+1
#define ROW (N_NODES * NDIM)                // 2002 floats per (k) row
#define SAMPLE_SLICE (N_WIDTH * ROW)        // 128128 floats per sample
#define SLICE4 (SAMPLE_SLICE / 4)           // 32032 float4 per sample slice
#define BUF_ELEMS ((long)N_COLL * SAMPLE_SLICE)  // 25,625,600 floats per buffer
#define COPY_BLOCKS 2048
#define RED_BLOCKS 64

typedef float f32x4 __attribute__((ext_vector_type(4)));

__device__ __forceinline__ float wave_reduce(float v) {
    for (int off = 32; off > 0; off >>= 1) v += __shfl_down(v, off, 64);
    return v;
}

// ---------------------------------------------------------------------------
// Fused kernel — R2 (504.0 us, best) with exactly ONE change: the 64 reduce
// blocks take ids [0, RED_BLOCKS) so they dispatch in the FIRST residency
// round and their ~12 us latency-bound work overlaps the copy instead of
// trailing it. Copy loop body is byte-identical to R2 (nt loads, skip-branch
// continue, no unroll) to keep codegen/VGPR pressure unchanged.
// ---------------------------------------------------------------------------
__global__ void fused_kernel(const float* __restrict__ x,
                             const int* __restrict__ flagp,
                             const int* __restrict__ samplep,
                             const float* __restrict__ weight,
                             const float* __restrict__ phi_in,
                             const float* __restrict__ dphi_in,
                             const float* __restrict__ ddphi_in,
                             float* __restrict__ phi_out,
                             float* __restrict__ dphi_out,
                             float* __restrict__ ddphi_out,
                             float* __restrict__ t_out) {
    const int sample = *samplep;
    const int tid = threadIdx.x;

    if (blockIdx.x >= RED_BLOCKS) {
        // ------------------ bulk pass-through copy (R2 body) ------------------
        const long skip_lo = (long)sample * SLICE4;
        const long skip_hi = skip_lo + SLICE4;
        const f32x4* __restrict__ a = (const f32x4*)phi_in;
        const f32x4* __restrict__ b = (const f32x4*)dphi_in;
        const f32x4* __restrict__ c = (const f32x4*)ddphi_in;
        f32x4* __restrict__ oa = (f32x4*)phi_out;
        f32x4* __restrict__ ob = (f32x4*)dphi_out;
        f32x4* __restrict__ oc = (f32x4*)ddphi_out;
        const long n4 = BUF_ELEMS / 4;
        long i = (long)(blockIdx.x - RED_BLOCKS) * 256 + tid;
        const long stride = (long)COPY_BLOCKS * 256;
        for (; i < n4; i += stride) {
            if (i >= skip_lo && i < skip_hi) continue;   // owned by reduce blocks
            f32x4 va = __builtin_nontemporal_load(a + i);
            f32x4 vb = __builtin_nontemporal_load(b + i);
            f32x4 vc = __builtin_nontemporal_load(c + i);
            oa[i] = va;   // regular stores: overwrite poison-dirty lines in cache
            ob[i] = vb;
            oc[i] = vc;
        }
        return;
    }

    // ------------------ sample-slice row k: scatter + copy + reduce ---------
    const int k = blockIdx.x;
    const int flag = *flagp;
    const long wbase = (long)k * ROW;
    const long base = (long)sample * SAMPLE_SLICE + wbase;

    // element lookup per input dimension (same for every k)
    float xs[NDIM];
    int nl[NDIM];
    for (int q = 0; q < NDIM; ++q) {
        xs[q] = (float)(N_NODES - 1) * x[q];            // X_MIN=0, X_MAX=1
        float id_el = floorf(xs[q] / (float)N_ORDER);
        id_el = fminf(fmaxf(id_el, 0.0f), (float)(N_ELEMENTS - 1));
        nl[q] = (int)(id_el * (float)N_ORDER);
    }

    // Lagrange bases on nodes {-1,-0.5,0,0.5,1} for both d channels
    const float nodes[MM] = {-1.0f, -0.5f, 0.0f, 0.5f, 1.0f};
    float L[NDIM][MM], dLv[NDIM][MM], ddLv[NDIM][MM];
    for (int d = 0; d < NDIM; ++d) {
        float xt = (xs[d] - ((float)nl[d] + 2.0f)) * 0.5f;
        float inv[MM][MM], r[MM][MM];
        for (int i = 0; i < MM; ++i)
            for (int kk = 0; kk < MM; ++kk) {
                inv[i][kk] = (i == kk) ? 0.0f : 1.0f / (nodes[i] - nodes[kk]);
                r[i][kk] = (xt - nodes[kk]) * inv[i][kk];
            }
        for (int i = 0; i < MM; ++i) {
            float prod = 1.0f;
            for (int kk = 0; kk < MM; ++kk) if (kk != i) prod *= r[i][kk];
            L[d][i] = prod;

            float s = 0.0f;
            for (int j = 0; j < MM; ++j) if (j != i) {
                float pr = 1.0f;
                for (int kk = 0; kk < MM; ++kk) if (kk != i && kk != j) pr *= r[i][kk];
                s += inv[i][j] * pr;
            }
            dLv[d][i] = (i == MM - 1) ? s : 0.0f;  // reference quirk: only i==M-1 kept

            float ss = 0.0f;
            for (int j = 0; j < MM; ++j) if (j != i) {
                float s2 = 0.0f;
                for (int kk = 0; kk < MM; ++kk) if (kk != i && kk != j) {
                    float pr = 1.0f;
                    for (int l = 0; l < MM; ++l) if (l != i && l != j && l != kk) pr *= r[i][l];
                    s2 += inv[i][kk] * pr;
                }
                ss += inv[i][j] * s2;
            }
            ddLv[d][i] = ss;
        }
    }

    const float dx = 0.5f * (float)N_ORDER / (float)(N_NODES - 1);  // 0.002
    const float inv_dx = 1.0f / dx;
    const float inv_dx2 = inv_dx * inv_dx;

    float st = 0.0f, sdt = 0.0f, sddt = 0.0f;
    for (int i = tid; i < ROW; i += 256) {
        float v   = phi_in[base + i];
        float dv  = dphi_in[base + i];
        float ddv = ddphi_in[base + i];
        if (flag == 0) {
            int q = i >> 1;
            int d = i & 1;
            // final reference write at (q,d): largest valid p over dq ranges
            int p0 = q - nl[0];
            int p1 = q - nl[1];
            int p = -1;
            if (p0 >= 0 && p0 <= N_ORDER) p = p0;
            if (p1 >= 0 && p1 <= N_ORDER && p1 > p) p = p1;
            if (p >= 0) {
                v   = L[d][p];
                dv  = dLv[d][p] * inv_dx;
                ddv = ddLv[d][p] * inv_dx2;
            }
        }
        phi_out[base + i]   = v;
        dphi_out[base + i]  = dv;
        ddphi_out[base + i] = ddv;
        float wv = weight[wbase + i];
        st   += wv * v;
        sdt  += wv * dv;
        sddt += wv * ddv;
    }

    st = wave_reduce(st);
    sdt = wave_reduce(sdt);
    sddt = wave_reduce(sddt);

    __shared__ float sh[3][4];
    int lane = tid & 63;
    int wid = tid >> 6;
    if (lane == 0) { sh[0][wid] = st; sh[1][wid] = sdt; sh[2][wid] = sddt; }
    __syncthreads();
    if (tid == 0) {
        t_out[k]       = sh[0][0] + sh[0][1] + sh[0][2] + sh[0][3];
        t_out[64 + k]  = sh[1][0] + sh[1][1] + sh[1][2] + sh[1][3];
        t_out[128 + k] = sh[2][0] + sh[2][1] + sh[2][2] + sh[2][3];
    }
}

extern "C" void kernel_launch(void* const* d_in, const int* in_sizes, int n_in,
                              void* d_out, int out_size, void* d_ws, size_t ws_size,
                              hipStream_t stream) {
    const float* x        = (const float*)d_in[0];
    const int*   flagp    = (const int*)d_in[1];
    const int*   samplep  = (const int*)d_in[2];
    const float* weight   = (const float*)d_in[3];
    const float* phi_in   = (const float*)d_in[4];
    const float* dphi_in  = (const float*)d_in[5];
    const float* ddphi_in = (const float*)d_in[6];

    float* out = (float*)d_out;
    float* t_out     = out;             // 192 floats: t(64), dt(64), ddt(64)
    float* phi_out   = out + 192;       // 768 B offset -> 16B aligned
    float* dphi_out  = phi_out + BUF_ELEMS;
    float* ddphi_out = dphi_out + BUF_ELEMS;

    fused_kernel<<<RED_BLOCKS + COPY_BLOCKS, 256, 0, stream>>>(
        x, flagp, samplep, weight, phi_in, dphi_in, ddphi_in,
        phi_out, dphi_out, ddphi_out, t_out);
}

// Round 6
// 496.195 us; speedup vs baseline: 1.0334x; 1.0241x over previous
//
#include <hip/hip_runtime.h>

#define N_WIDTH 64
#define N_ORDER 4
#define N_ELEMENTS 250
#define N_NODES 1001                        // N_ELEMENTS*N_ORDER+1
#define N_COLL 200
#define NDIM 2
#define MM 5                                // N_ORDER+1
#define ROW (N_NODES * NDIM)                // 2002 floats per (k) row
#define SAMPLE_SLICE (N_WIDTH * ROW)        // 128128 floats per sample
#define SLICE4 (SAMPLE_SLICE / 4)           // 32032 float4 per sample slice
#define BUF_ELEMS ((long)N_COLL * SAMPLE_SLICE)  // 25,625,600 floats per buffer
#define GRP 683                             // copy blocks per buffer
#define COPY_BLOCKS (3 * GRP)               // 2049
#define RED_BLOCKS 64

typedef float f32x4 __attribute__((ext_vector_type(4)));

__device__ __forceinline__ float wave_reduce(float v) {
    for (int off = 32; off > 0; off >>= 1) v += __shfl_down(v, off, 64);
    return v;
}

// ---------------------------------------------------------------------------
// Fused kernel — R2 (504.0 us, best) with exactly ONE change: copy blocks are
// partitioned into 3 contiguous groups, each streaming ONE buffer (2 address
// streams per wave instead of 6), matching the 2-stream structure of the
// 6.29 TB/s copy microbenchmark. Everything else identical to R2: nt loads,
// regular stores, skip-branch continue, reduce blocks at the high block ids.
// ---------------------------------------------------------------------------
__global__ void fused_kernel(const float* __restrict__ x,
                             const int* __restrict__ flagp,
                             const int* __restrict__ samplep,
                             const float* __restrict__ weight,
                             const float* __restrict__ phi_in,
                             const float* __restrict__ dphi_in,
                             const float* __restrict__ ddphi_in,
                             float* __restrict__ phi_out,
                             float* __restrict__ dphi_out,
                             float* __restrict__ ddphi_out,
                             float* __restrict__ t_out) {
    const int sample = *samplep;
    const int tid = threadIdx.x;

    if (blockIdx.x < COPY_BLOCKS) {
        // ---------- bulk pass-through copy: one buffer per block group ------
        const int g   = blockIdx.x / GRP;            // 0,1,2 -> phi,dphi,ddphi
        const int bid = blockIdx.x - g * GRP;        // 0..GRP-1 within group
        const long skip_lo = (long)sample * SLICE4;
        const long skip_hi = skip_lo + SLICE4;
        const f32x4* __restrict__ in4 =
            (g == 0) ? (const f32x4*)phi_in :
            (g == 1) ? (const f32x4*)dphi_in : (const f32x4*)ddphi_in;
        f32x4* __restrict__ out4 =
            (g == 0) ? (f32x4*)phi_out :
            (g == 1) ? (f32x4*)dphi_out : (f32x4*)ddphi_out;
        const long n4 = BUF_ELEMS / 4;
        long i = (long)bid * 256 + tid;
        const long stride = (long)GRP * 256;
        for (; i < n4; i += stride) {
            if (i >= skip_lo && i < skip_hi) continue;   // owned by reduce blocks
            f32x4 v = __builtin_nontemporal_load(in4 + i);
            out4[i] = v;   // regular store: overwrite poison lines in cache
        }
        return;
    }

    // ------------------ sample-slice row k: scatter + copy + reduce ---------
    const int k = blockIdx.x - COPY_BLOCKS;
    const int flag = *flagp;
    const long wbase = (long)k * ROW;
    const long base = (long)sample * SAMPLE_SLICE + wbase;

    // element lookup per input dimension (same for every k)
    float xs[NDIM];
    int nl[NDIM];
    for (int q = 0; q < NDIM; ++q) {
        xs[q] = (float)(N_NODES - 1) * x[q];            // X_MIN=0, X_MAX=1
        float id_el = floorf(xs[q] / (float)N_ORDER);
        id_el = fminf(fmaxf(id_el, 0.0f), (float)(N_ELEMENTS - 1));
        nl[q] = (int)(id_el * (float)N_ORDER);
    }

    // Lagrange bases on nodes {-1,-0.5,0,0.5,1} for both d channels
    const float nodes[MM] = {-1.0f, -0.5f, 0.0f, 0.5f, 1.0f};
    float L[NDIM][MM], dLv[NDIM][MM], ddLv[NDIM][MM];
    for (int d = 0; d < NDIM; ++d) {
        float xt = (xs[d] - ((float)nl[d] + 2.0f)) * 0.5f;
        float inv[MM][MM], r[MM][MM];
        for (int i = 0; i < MM; ++i)
            for (int kk = 0; kk < MM; ++kk) {
                inv[i][kk] = (i == kk) ? 0.0f : 1.0f / (nodes[i] - nodes[kk]);
                r[i][kk] = (xt - nodes[kk]) * inv[i][kk];
            }
        for (int i = 0; i < MM; ++i) {
            float prod = 1.0f;
            for (int kk = 0; kk < MM; ++kk) if (kk != i) prod *= r[i][kk];
            L[d][i] = prod;

            float s = 0.0f;
            for (int j = 0; j < MM; ++j) if (j != i) {
                float pr = 1.0f;
                for (int kk = 0; kk < MM; ++kk) if (kk != i && kk != j) pr *= r[i][kk];
                s += inv[i][j] * pr;
            }
            dLv[d][i] = (i == MM - 1) ? s : 0.0f;  // reference quirk: only i==M-1 kept

            float ss = 0.0f;
            for (int j = 0; j < MM; ++j) if (j != i) {
                float s2 = 0.0f;
                for (int kk = 0; kk < MM; ++kk) if (kk != i && kk != j) {
                    float pr = 1.0f;
                    for (int l = 0; l < MM; ++l) if (l != i && l != j && l != kk) pr *= r[i][l];
                    s2 += inv[i][kk] * pr;
                }
                ss += inv[i][j] * s2;
            }
            ddLv[d][i] = ss;
        }
    }

    const float dx = 0.5f * (float)N_ORDER / (float)(N_NODES - 1);  // 0.002
    const float inv_dx = 1.0f / dx;
    const float inv_dx2 = inv_dx * inv_dx;

    float st = 0.0f, sdt = 0.0f, sddt = 0.0f;
    for (int i = tid; i < ROW; i += 256) {
        float v   = phi_in[base + i];
        float dv  = dphi_in[base + i];
        float ddv = ddphi_in[base + i];
        if (flag == 0) {
            int q = i >> 1;
            int d = i & 1;
            // final reference write at (q,d): largest valid p over dq ranges
            int p0 = q - nl[0];
            int p1 = q - nl[1];
            int p = -1;
            if (p0 >= 0 && p0 <= N_ORDER) p = p0;
            if (p1 >= 0 && p1 <= N_ORDER && p1 > p) p = p1;
            if (p >= 0) {
                v   = L[d][p];
                dv  = dLv[d][p] * inv_dx;
                ddv = ddLv[d][p] * inv_dx2;
            }
        }
        phi_out[base + i]   = v;
        dphi_out[base + i]  = dv;
        ddphi_out[base + i] = ddv;
        float wv = weight[wbase + i];
        st   += wv * v;
        sdt  += wv * dv;
        sddt += wv * ddv;
    }

    st = wave_reduce(st);
    sdt = wave_reduce(sdt);
    sddt = wave_reduce(sddt);

    __shared__ float sh[3][4];
    int lane = tid & 63;
    int wid = tid >> 6;
    if (lane == 0) { sh[0][wid] = st; sh[1][wid] = sdt; sh[2][wid] = sddt; }
    __syncthreads();
    if (tid == 0) {
        t_out[k]       = sh[0][0] + sh[0][1] + sh[0][2] + sh[0][3];
        t_out[64 + k]  = sh[1][0] + sh[1][1] + sh[1][2] + sh[1][3];
        t_out[128 + k] = sh[2][0] + sh[2][1] + sh[2][2] + sh[2][3];
    }
}

extern "C" void kernel_launch(void* const* d_in, const int* in_sizes, int n_in,
                              void* d_out, int out_size, void* d_ws, size_t ws_size,
                              hipStream_t stream) {
    const float* x        = (const float*)d_in[0];
    const int*   flagp    = (const int*)d_in[1];
    const int*   samplep  = (const int*)d_in[2];
    const float* weight   = (const float*)d_in[3];
    const float* phi_in   = (const float*)d_in[4];
    const float* dphi_in  = (const float*)d_in[5];
    const float* ddphi_in = (const float*)d_in[6];

    float* out = (float*)d_out;
    float* t_out     = out;             // 192 floats: t(64), dt(64), ddt(64)
    float* phi_out   = out + 192;       // 768 B offset -> 16B aligned
    float* dphi_out  = phi_out + BUF_ELEMS;
    float* ddphi_out = dphi_out + BUF_ELEMS;

    fused_kernel<<<COPY_BLOCKS + RED_BLOCKS, 256, 0, stream>>>(
        x, flagp, samplep, weight, phi_in, dphi_in, ddphi_in,
        phi_out, dphi_out, ddphi_out, t_out);
}